// Round 11
// baseline (346.660 us; speedup 1.0000x reference)
//
#include <hip/hip_runtime.h>
#include <hip/hip_bf16.h>
#include <math.h>

// MFGN forward, MI355X. One block (512 thr, 8 waves) per outfit.
// fp32 facL state in LDS; bf16 featB state in MFMA A-layout (Phase D destaged);
// separate prod/hid buffers (B: 3 barriers/step).
// Phase B candidate-tile skip via RUNTIME loop `for(mt<mtn)` with a fresh
// single acc per iteration — NOT `if(mt<mtn)` inside unrolled loops, which
// created conditional acc defs and 127-151MB scratch spill (R8/R9 lesson).
// Kernel is near LDS-BW-bound (each wave re-reads all of prodS/hidS per step);
// mtn-loop cuts that traffic + MFMA ~25% at typical nc=11-12.

typedef __attribute__((ext_vector_type(8))) short short8;
typedef __attribute__((ext_vector_type(4))) float f32x4;

#define MFMA16(a, b, c) __builtin_amdgcn_mfma_f32_16x16x32_bf16(a, b, c, 0, 0, 0)

__device__ __forceinline__ float lrelu(float x) { return x > 0.0f ? x : 0.01f * x; }

__device__ __forceinline__ ushort f2bf(float f) {
  unsigned u = __builtin_bit_cast(unsigned, f);
  u += 0x7fffu + ((u >> 16) & 1u);  // RNE
  return (ushort)(u >> 16);
}
__device__ __forceinline__ float bflo(unsigned u) {
  return __builtin_bit_cast(float, u << 16);
}
__device__ __forceinline__ unsigned pk2(float a, float b) {
  float2 t; t.x = a; t.y = b;
  __hip_bfloat162 h = __float22bfloat162_rn(t);
  unsigned u;
  __builtin_memcpy(&u, &h, 4);
  return u;
}
__device__ __forceinline__ short8 load_bfrag(const float* __restrict__ W, int ldn,
                                             int kbase, int col) {
  short8 r;
#pragma unroll
  for (int j = 0; j < 8; ++j) r[j] = (short)f2bf(W[(kbase + j) * ldn + col]);
  return r;
}

__global__ void zero_com(float* out) { if (threadIdx.x == 0) out[2048] = 0.0f; }

__global__ __launch_bounds__(512, 4) void mfgn_kernel(
    const int* __restrict__ outfit_items,
    const float* __restrict__ items_feature,
    const int* __restrict__ items_neighbor,
    const float* __restrict__ cfW1, const float* __restrict__ cfb1,
    const float* __restrict__ cfW2, const float* __restrict__ cfb2,
    const float* __restrict__ f2fW1, const float* __restrict__ f2fb1,
    const float* __restrict__ f2fW2, const float* __restrict__ f2fb2,
    const float* __restrict__ f2iW1, const float* __restrict__ f2ib1,
    const float* __restrict__ f2iW2, const float* __restrict__ f2ib2,
    const float* __restrict__ i2iW1, const float* __restrict__ i2ib1,
    const float* __restrict__ i2iW2, const float* __restrict__ i2ib2,
    const float* __restrict__ o2sW, const float* __restrict__ o2sb,
    float* __restrict__ out)
{
  __shared__ float facL[16 * 528];                                 // 33792 B fp32 state
  __shared__ ushort prodS[64 * 136] __attribute__((aligned(16)));  // 17408 B bf16 A-staging
  __shared__ ushort hidS[64 * 136] __attribute__((aligned(16)));   // 17408 B bf16 hidden
  __shared__ ushort featB[16 * 136] __attribute__((aligned(16)));  //  4352 B bf16 feat state
  __shared__ float redE[8];
  __shared__ int oiL[16];
  __shared__ int clAll[256];
  __shared__ int ncAll[16];
  __shared__ int vslL[16];
  __shared__ int refcntL[16];
  __shared__ int nvsL;

  const int o = blockIdx.x;
  const int tid = (int)threadIdx.x;
  const int lane = tid & 63;
  const int wid = tid >> 6;        // wave owns output cols wid*16..+15
  const int n16 = lane & 15;
  const int q = lane >> 4;
  const int kb = q * 8;
  const int col = wid * 16 + n16;

  // ---------------- load inputs ----------------
  if (tid < 16) oiL[tid] = outfit_items[o * 16 + tid];
  {
    const int n = tid >> 5, d0 = (tid & 31) * 4;
    float4 v = *(const float4*)(items_feature + o * 2048 + tid * 4);
    uint2 pk; pk.x = pk2(v.x, v.y); pk.y = pk2(v.z, v.w);
    *(uint2*)(featB + n * 136 + d0) = pk;
  }
  if (tid == 0) {
    int cnt = 0;
    for (int s = 0; s < 16; ++s) refcntL[s] = 0;
    for (int s = 0; s < 16; ++s) {
      int v = oiL[s];
      if (v != -1) { vslL[cnt++] = s; refcntL[v]++; }
    }
    nvsL = cnt;
  }
  for (int s = wid; s < 16; s += 8) {
    const int iv = outfit_items[o * 16 + s];
    if (iv == -1) { if (lane == 0) ncAll[s] = 0; continue; }
    int cand = -1;
    if (lane < 24) cand = (lane < 16) ? outfit_items[o * 16 + lane]
                                      : items_neighbor[o * 128 + iv * 8 + (lane - 16)];
    bool ok = (lane < 24) && (cand != -1) && (cand != iv);
    unsigned long long bm = __ballot(ok);
    if (ok) clAll[s * 16 + __popcll(bm & ((1ull << lane) - 1ull))] = cand;
    if (lane == 0) ncAll[s] = (int)__popcll(bm);
  }
  __syncthreads();
  const int nvs = nvsL;

  // ---------------- Phase A: creat_factors ----------------
  {
    const int f = wid & 3, half = wid >> 2;
    short8 wA[2][4];
#pragma unroll
    for (int etl = 0; etl < 2; ++etl)
#pragma unroll
      for (int kt = 0; kt < 4; ++kt)
        wA[etl][kt] = load_bfrag(cfW1 + f * 8192, 64, kt * 32 + kb, (half * 2 + etl) * 16 + n16);
    f32x4 acc[2];
    acc[0] = (f32x4){0.f,0.f,0.f,0.f}; acc[1] = (f32x4){0.f,0.f,0.f,0.f};
    for (int kt = 0; kt < 4; ++kt) {
      short8 x = *(const short8*)(featB + n16 * 136 + kt * 32 + kb);
      acc[0] = MFMA16(wA[0][kt], x, acc[0]);
      acc[1] = MFMA16(wA[1][kt], x, acc[1]);
    }
#pragma unroll
    for (int etl = 0; etl < 2; ++etl) {
      f32x4 b1q = *(const f32x4*)(cfb1 + f * 64 + (half * 2 + etl) * 16 + q * 4);
      float h0 = lrelu(acc[etl][0] + b1q[0]), h1 = lrelu(acc[etl][1] + b1q[1]);
      float h2 = lrelu(acc[etl][2] + b1q[2]), h3 = lrelu(acc[etl][3] + b1q[3]);
      uint2 pk; pk.x = pk2(h0, h1); pk.y = pk2(h2, h3);
      *(uint2*)(hidS + (f * 16 + n16) * 136 + (half * 2 + etl) * 16 + q * 4) = pk;
    }
    __syncthreads();
    short8 wB[4][2];
#pragma unroll
    for (int ctl = 0; ctl < 4; ++ctl)
#pragma unroll
      for (int kt = 0; kt < 2; ++kt)
        wB[ctl][kt] = load_bfrag(cfW2 + f * 8192, 128, kt * 32 + kb, half * 64 + ctl * 16 + n16);
    f32x4 acc2[4];
#pragma unroll
    for (int ctl = 0; ctl < 4; ++ctl) acc2[ctl] = (f32x4){0.f,0.f,0.f,0.f};
    for (int kt = 0; kt < 2; ++kt) {
      short8 h = *(const short8*)(hidS + (f * 16 + n16) * 136 + kt * 32 + kb);
#pragma unroll
      for (int ctl = 0; ctl < 4; ++ctl) acc2[ctl] = MFMA16(h, wB[ctl][kt], acc2[ctl]);
    }
#pragma unroll
    for (int ctl = 0; ctl < 4; ++ctl) {
      int c = half * 64 + ctl * 16 + n16;
      float b2 = cfb2[f * 128 + c];
#pragma unroll
      for (int r = 0; r < 4; ++r)
        facL[(q * 4 + r) * 528 + f * 132 + c] = lrelu(acc2[ctl][r] + b2);
    }
    __syncthreads();
  }

  // ---------------- Phase B: inter_factors (fp32 facL state) ----------------
  {
    short8 w1f[4], w2f[4];
#pragma unroll
    for (int kt = 0; kt < 4; ++kt) {
      w1f[kt] = load_bfrag(f2fW1, 128, kt * 32 + kb, col);
      w2f[kt] = load_bfrag(f2fW2, 128, kt * 32 + kb, col);
    }
    const f32x4 b1q = *(const f32x4*)(f2fb1 + wid * 16 + q * 4);
    const float b2v = f2fb2[col];
    const int rS = tid >> 3, kcS = tid & 7;   // staging: row, 16-value k-chunk
    const int fS = rS & 3, ciS = rS >> 2;
    const int k0 = kcS * 16;

    for (int s = 0; s < 16; ++s) {
      const int iv = oiL[s];
      if (iv == -1) continue;
      const int nc = ncAll[s];
      const int mtn = (nc + 3) >> 2;  // tiles actually consumed below
      // stage prod[r=ci*4+f][k] = bf16(fac[iv][f][k] * fac[cand][f][k])
      if (ciS < nc) {
        const int cit = clAll[s * 16 + ciS];
        const float* tp = facL + iv * 528 + fS * 132;
        const float* cp = facL + cit * 528 + fS * 132;
#pragma unroll
        for (int i2 = 0; i2 < 2; ++i2) {
          const int k = k0 + i2 * 8;
          float4 a0 = *(const float4*)(tp + k), a1 = *(const float4*)(tp + k + 4);
          float4 c0 = *(const float4*)(cp + k), c1 = *(const float4*)(cp + k + 4);
          uint4 u;
          u.x = pk2(a0.x * c0.x, a0.y * c0.y); u.y = pk2(a0.z * c0.z, a0.w * c0.w);
          u.z = pk2(a1.x * c1.x, a1.y * c1.y); u.w = pk2(a1.z * c1.z, a1.w * c1.w);
          *(uint4*)(prodS + rS * 136 + k) = u;
        }
      } else if (ciS < mtn * 4) {  // zero only rows inside consumed tiles
        uint4 z; z.x = z.y = z.z = z.w = 0;
        *(uint4*)(prodS + rS * 136 + k0) = z;
        *(uint4*)(prodS + rS * 136 + k0 + 8) = z;
      }
      __syncthreads();  // [b1] products ready
      // L1 swapped: runtime mt-loop, fresh acc per iter (no conditional defs)
      for (int mt = 0; mt < mtn; ++mt) {
        f32x4 acc = (f32x4){0.f,0.f,0.f,0.f};
#pragma unroll
        for (int kt = 0; kt < 4; ++kt) {
          short8 x = *(const short8*)(prodS + (mt * 16 + n16) * 136 + kt * 32 + kb);
          acc = MFMA16(w1f[kt], x, acc);
        }
        float h0 = lrelu(acc[0] + b1q[0]), h1 = lrelu(acc[1] + b1q[1]);
        float h2 = lrelu(acc[2] + b1q[2]), h3 = lrelu(acc[3] + b1q[3]);
        uint2 pk; pk.x = pk2(h0, h1); pk.y = pk2(h2, h3);
        *(uint2*)(hidS + (mt * 16 + n16) * 136 + wid * 16 + q * 4) = pk;
      }
      __syncthreads();  // [b2] hid ready
      // L2 normal: runtime mt-loop; accumulate masked row-sums into part[]
      float part[4] = {0.f, 0.f, 0.f, 0.f};
      for (int mt = 0; mt < mtn; ++mt) {
        f32x4 acc2 = (f32x4){0.f,0.f,0.f,0.f};
#pragma unroll
        for (int kt = 0; kt < 4; ++kt) {
          short8 h = *(const short8*)(hidS + (mt * 16 + n16) * 136 + kt * 32 + kb);
          acc2 = MFMA16(h, w2f[kt], acc2);
        }
        bool act = (mt * 4 + q) < nc;
        if (act) {
#pragma unroll
          for (int r = 0; r < 4; ++r) part[r] += lrelu(acc2[r] + b2v);
        }
      }
#pragma unroll
      for (int r = 0; r < 4; ++r) {
        float v = part[r];
        v += __shfl_xor(v, 16);
        v += __shfl_xor(v, 32);
        part[r] = v;
      }
      if (q == 0) {  // wave owns cols exclusively -> plain fp32 +=
#pragma unroll
        for (int r = 0; r < 4; ++r)
          facL[iv * 528 + r * 132 + col] += part[r];
      }
      __syncthreads();  // [b3] facL updated for next step's stage
    }
  }

  // ---------------- Phase C: infer_items ----------------
  {
    short8 w1f[4], w2f[4];
#pragma unroll
    for (int kt = 0; kt < 4; ++kt) {
      w1f[kt] = load_bfrag(f2iW1, 128, kt * 32 + kb, col);
      w2f[kt] = load_bfrag(f2iW2, 128, kt * 32 + kb, col);
    }
    const f32x4 b1q = *(const f32x4*)(f2ib1 + wid * 16 + q * 4);
    const float b2v = f2ib2[col];
    // stage prod[r=item*4+f][k] = bf16(fac[item][f][k])
    {
      const int r = tid >> 3, kc = tid & 7, k0 = kc * 16;
      const int f = r & 3, item = r >> 2;
      const float* sp = facL + item * 528 + f * 132;
#pragma unroll
      for (int i2 = 0; i2 < 2; ++i2) {
        const int k = k0 + i2 * 8;
        float4 a0 = *(const float4*)(sp + k), a1 = *(const float4*)(sp + k + 4);
        uint4 u;
        u.x = pk2(a0.x, a0.y); u.y = pk2(a0.z, a0.w);
        u.z = pk2(a1.x, a1.y); u.w = pk2(a1.z, a1.w);
        *(uint4*)(prodS + r * 136 + k) = u;
      }
    }
    __syncthreads();
    f32x4 acc[4];
#pragma unroll
    for (int mt = 0; mt < 4; ++mt) acc[mt] = (f32x4){0.f,0.f,0.f,0.f};
    for (int kt = 0; kt < 4; ++kt)
#pragma unroll
      for (int mt = 0; mt < 4; ++mt) {
        short8 x = *(const short8*)(prodS + (mt * 16 + n16) * 136 + kt * 32 + kb);
        acc[mt] = MFMA16(w1f[kt], x, acc[mt]);
      }
#pragma unroll
    for (int mt = 0; mt < 4; ++mt) {
      float h0 = lrelu(acc[mt][0] + b1q[0]), h1 = lrelu(acc[mt][1] + b1q[1]);
      float h2 = lrelu(acc[mt][2] + b1q[2]), h3 = lrelu(acc[mt][3] + b1q[3]);
      uint2 pk; pk.x = pk2(h0, h1); pk.y = pk2(h2, h3);
      *(uint2*)(hidS + (mt * 16 + n16) * 136 + wid * 16 + q * 4) = pk;
    }
    __syncthreads();
    f32x4 acc2[4];
#pragma unroll
    for (int mt = 0; mt < 4; ++mt) acc2[mt] = (f32x4){0.f,0.f,0.f,0.f};
    for (int kt = 0; kt < 4; ++kt)
#pragma unroll
      for (int mt = 0; mt < 4; ++mt) {
        short8 h = *(const short8*)(hidS + (mt * 16 + n16) * 136 + kt * 32 + kb);
        acc2[mt] = MFMA16(h, w2f[kt], acc2[mt]);
      }
#pragma unroll
    for (int mt = 0; mt < 4; ++mt) {
      int item = mt * 4 + q;  // rows = item*4+f, f=reg
      float g = 0.f;
#pragma unroll
      for (int r = 0; r < 4; ++r) g += lrelu(acc2[mt][r] + b2v);
      int a = item * 136 + col;  // unique (item,col) per lane
      featB[a] = f2bf(bflo((unsigned)featB[a]) + (float)refcntL[item] * g);
    }
    __syncthreads();
  }

  // ---------------- Phase D: inter_items (featB IS the A operand) ----------------
  {
    short8 w1f[4], w2f[4];
#pragma unroll
    for (int kt = 0; kt < 4; ++kt) {
      w1f[kt] = load_bfrag(i2iW1, 128, kt * 32 + kb, col);
      w2f[kt] = load_bfrag(i2iW2, 128, kt * 32 + kb, col);
    }
    const f32x4 b1q = *(const f32x4*)(i2ib1 + wid * 16 + q * 4);
    const float b2v = i2ib2[col];

    for (int u = 0; u < nvs; ++u) {
      const int iv = oiL[vslL[u]];
      f32x4 acc = (f32x4){0.f,0.f,0.f,0.f};
      for (int kt = 0; kt < 4; ++kt) {
        short8 x = *(const short8*)(featB + n16 * 136 + kt * 32 + kb);
        acc = MFMA16(w1f[kt], x, acc);
      }
      {
        float h0 = lrelu(acc[0] + b1q[0]), h1 = lrelu(acc[1] + b1q[1]);
        float h2 = lrelu(acc[2] + b1q[2]), h3 = lrelu(acc[3] + b1q[3]);
        uint2 pk; pk.x = pk2(h0, h1); pk.y = pk2(h2, h3);
        *(uint2*)(hidS + n16 * 136 + wid * 16 + q * 4) = pk;
      }
      __syncthreads();
      f32x4 acc2 = (f32x4){0.f,0.f,0.f,0.f};
      for (int kt = 0; kt < 4; ++kt) {
        short8 h = *(const short8*)(hidS + n16 * 136 + kt * 32 + kb);
        acc2 = MFMA16(h, w2f[kt], acc2);
      }
      // msgs summed per item with weight = (item==iv) ? 0 : refcnt[item]
      float part = 0.f;
#pragma unroll
      for (int r = 0; r < 4; ++r) {
        int item = q * 4 + r;
        float w = (item == iv) ? 0.0f : (float)refcntL[item];
        part += w * lrelu(acc2[r] + b2v);
      }
      part += __shfl_xor(part, 16);
      part += __shfl_xor(part, 32);
      if (q == 0) {
        int a = iv * 136 + col;
        featB[a] = f2bf(bflo((unsigned)featB[a]) + part);
      }
      __syncthreads();
    }
  }

  // ---------------- Phase E: infer_outfit + score ----------------
  if (tid < 128) {
    float sum = 0.0f;
    for (int u = 0; u < nvs; ++u)
      sum += bflo((unsigned)featB[oiL[vslL[u]] * 136 + tid]);
    float v = sum * o2sW[tid];
#pragma unroll
    for (int off = 1; off < 64; off <<= 1) v += __shfl_xor(v, off);
    if (lane == 0) redE[wid] = v;
  }
  __syncthreads();
  if (tid == 0) {
    float t = redE[0] + redE[1] + o2sb[0];
    out[o] = 1.0f / (1.0f + expf(-t));
  }

  // ---------------- Phase F: com_loss from fp32 facL ----------------
  {
    const int n = tid >> 5, f = (tid >> 3) & 3, g = (tid >> 1) & 3, h = tid & 1;
    const float* pa = facL + n * 528 + f * 132 + h * 64;
    const float* pb = facL + n * 528 + g * 132 + h * 64;
    float dot = 0.0f;
    for (int i = 0; i < 16; ++i) {
      float4 a = *(const float4*)(pa + i * 4);
      float4 b = *(const float4*)(pb + i * 4);
      dot += a.x * b.x + a.y * b.y + a.z * b.z + a.w * b.w;
    }
    dot += __shfl_xor(dot, 1);  // combine k-halves
    float v = dot - ((f == g) ? 1.0f : 0.0f);
    float sq = (h == 0 && oiL[n] != -1) ? v * v : 0.0f;
#pragma unroll
    for (int off = 1; off < 64; off <<= 1) sq += __shfl_xor(sq, off);
    __syncthreads();  // E's redE read complete before overwrite
    if (lane == 0) redE[wid] = sq;
    __syncthreads();
    if (tid == 0) {
      float tot = 0.f;
#pragma unroll
      for (int w = 0; w < 8; ++w) tot += redE[w];
      atomicAdd(out + 2048, tot * (1.0f / 2048.0f));
    }
  }
}

extern "C" void kernel_launch(void* const* d_in, const int* in_sizes, int n_in,
                              void* d_out, int out_size, void* d_ws, size_t ws_size,
                              hipStream_t stream) {
  float* out = (float*)d_out;
  hipLaunchKernelGGL(zero_com, dim3(1), dim3(64), 0, stream, out);
  hipLaunchKernelGGL(mfgn_kernel, dim3(2048), dim3(512), 0, stream,
                     (const int*)d_in[0],
                     (const float*)d_in[1],
                     (const int*)d_in[2],
                     // d_in[3] items_factors unused (overwritten by creat_factors)
                     (const float*)d_in[4], (const float*)d_in[5],
                     (const float*)d_in[6], (const float*)d_in[7],
                     (const float*)d_in[8], (const float*)d_in[9],
                     (const float*)d_in[10], (const float*)d_in[11],
                     (const float*)d_in[12], (const float*)d_in[13],
                     (const float*)d_in[14], (const float*)d_in[15],
                     (const float*)d_in[16], (const float*)d_in[17],
                     (const float*)d_in[18], (const float*)d_in[19],
                     (const float*)d_in[20], (const float*)d_in[21],
                     out);
}

// Round 12
// 340.407 us; speedup vs baseline: 1.0184x; 1.0184x over previous
//
#include <hip/hip_runtime.h>
#include <hip/hip_bf16.h>
#include <math.h>

// MFGN forward, MI355X. One block (512 thr, 8 waves) per outfit.
// fp32 facL state in LDS; bf16 featB state in MFMA A-layout (Phase D destaged);
// separate prod/hid buffers (B: 3 barriers/step); runtime mt-loop (no
// conditional acc defs -> no spill, R8/R9 lesson).
// NEW (R12): weights pre-transposed to bf16 [N][K] B-fragment layout in d_ws
// by a prep kernel -> each fragment is ONE global_load_dwordx4 (was 8 scalar
// loads + 8 cvt per fragment; ~1000 VALU/lane total). Same f2bf RNE ->
// bit-identical numerics.

typedef __attribute__((ext_vector_type(8))) short short8;
typedef __attribute__((ext_vector_type(4))) float f32x4;

#define MFMA16(a, b, c) __builtin_amdgcn_mfma_f32_16x16x32_bf16(a, b, c, 0, 0, 0)

__device__ __forceinline__ float lrelu(float x) { return x > 0.0f ? x : 0.01f * x; }

__device__ __forceinline__ ushort f2bf(float f) {
  unsigned u = __builtin_bit_cast(unsigned, f);
  u += 0x7fffu + ((u >> 16) & 1u);  // RNE
  return (ushort)(u >> 16);
}
__device__ __forceinline__ float bflo(unsigned u) {
  return __builtin_bit_cast(float, u << 16);
}
__device__ __forceinline__ unsigned pk2(float a, float b) {
  float2 t; t.x = a; t.y = b;
  __hip_bfloat162 h = __float22bfloat162_rn(t);
  unsigned u;
  __builtin_memcpy(&u, &h, 4);
  return u;
}

// d_ws layout (ushort elements):
//   cfW1T  @ 0      [4][64n][128k]
//   cfW2T  @ 32768  [4][128n][64k]
//   f2fW1T @ 65536  [128n][128k]   f2fW2T @ 81920
//   f2iW1T @ 98304                 f2iW2T @ 114688
//   i2iW1T @ 131072                i2iW2T @ 147456   (total 163840 el = 320KB)

__global__ __launch_bounds__(256) void prep_weights(
    const float* __restrict__ cfW1, const float* __restrict__ cfW2,
    const float* __restrict__ f2fW1, const float* __restrict__ f2fW2,
    const float* __restrict__ f2iW1, const float* __restrict__ f2iW2,
    const float* __restrict__ i2iW1, const float* __restrict__ i2iW2,
    ushort* __restrict__ ws, float* __restrict__ out) {
  const int idx = (int)(blockIdx.x * 256 + threadIdx.x);
  if (idx == 0) out[2048] = 0.0f;  // com accumulator zero (folded zero_com)
  float v;
  if (idx < 32768) {          // cfW1 [f][k<128][n<64] -> [f][n][k]
    int f = idx >> 13, r = idx & 8191, n = r >> 7, k = r & 127;
    v = cfW1[f * 8192 + k * 64 + n];
  } else if (idx < 65536) {   // cfW2 [f][k<64][n<128] -> [f][n][k]
    int t = idx - 32768;
    int f = t >> 13, r = t & 8191, n = r >> 6, k = r & 63;
    v = cfW2[f * 8192 + k * 128 + n];
  } else {                    // 6 x [k<128][n<128] -> [n][k]
    int t = idx - 65536;
    int seg = t >> 14, r = t & 16383, n = r >> 7, k = r & 127;
    const float* W = (seg == 0) ? f2fW1 : (seg == 1) ? f2fW2 :
                     (seg == 2) ? f2iW1 : (seg == 3) ? f2iW2 :
                     (seg == 4) ? i2iW1 : i2iW2;
    v = W[k * 128 + n];
  }
  ws[idx] = f2bf(v);
}

__global__ __launch_bounds__(512, 4) void mfgn_kernel(
    const int* __restrict__ outfit_items,
    const float* __restrict__ items_feature,
    const int* __restrict__ items_neighbor,
    const float* __restrict__ cfb1, const float* __restrict__ cfb2,
    const float* __restrict__ f2fb1, const float* __restrict__ f2fb2,
    const float* __restrict__ f2ib1, const float* __restrict__ f2ib2,
    const float* __restrict__ i2ib1, const float* __restrict__ i2ib2,
    const float* __restrict__ o2sW, const float* __restrict__ o2sb,
    const ushort* __restrict__ wsW,
    float* __restrict__ out)
{
  __shared__ float facL[16 * 528];                                 // 33792 B fp32 state
  __shared__ ushort prodS[64 * 136] __attribute__((aligned(16)));  // 17408 B bf16 A-staging
  __shared__ ushort hidS[64 * 136] __attribute__((aligned(16)));   // 17408 B bf16 hidden
  __shared__ ushort featB[16 * 136] __attribute__((aligned(16)));  //  4352 B bf16 feat state
  __shared__ float redE[8];
  __shared__ int oiL[16];
  __shared__ int clAll[256];
  __shared__ int ncAll[16];
  __shared__ int vslL[16];
  __shared__ int refcntL[16];
  __shared__ int nvsL;

  const int o = blockIdx.x;
  const int tid = (int)threadIdx.x;
  const int lane = tid & 63;
  const int wid = tid >> 6;        // wave owns output cols wid*16..+15
  const int n16 = lane & 15;
  const int q = lane >> 4;
  const int kb = q * 8;
  const int col = wid * 16 + n16;

  // ---------------- load inputs ----------------
  if (tid < 16) oiL[tid] = outfit_items[o * 16 + tid];
  {
    const int n = tid >> 5, d0 = (tid & 31) * 4;
    float4 v = *(const float4*)(items_feature + o * 2048 + tid * 4);
    uint2 pk; pk.x = pk2(v.x, v.y); pk.y = pk2(v.z, v.w);
    *(uint2*)(featB + n * 136 + d0) = pk;
  }
  if (tid == 0) {
    int cnt = 0;
    for (int s = 0; s < 16; ++s) refcntL[s] = 0;
    for (int s = 0; s < 16; ++s) {
      int v = oiL[s];
      if (v != -1) { vslL[cnt++] = s; refcntL[v]++; }
    }
    nvsL = cnt;
  }
  for (int s = wid; s < 16; s += 8) {
    const int iv = outfit_items[o * 16 + s];
    if (iv == -1) { if (lane == 0) ncAll[s] = 0; continue; }
    int cand = -1;
    if (lane < 24) cand = (lane < 16) ? outfit_items[o * 16 + lane]
                                      : items_neighbor[o * 128 + iv * 8 + (lane - 16)];
    bool ok = (lane < 24) && (cand != -1) && (cand != iv);
    unsigned long long bm = __ballot(ok);
    if (ok) clAll[s * 16 + __popcll(bm & ((1ull << lane) - 1ull))] = cand;
    if (lane == 0) ncAll[s] = (int)__popcll(bm);
  }
  __syncthreads();
  const int nvs = nvsL;

  // ---------------- Phase A: creat_factors ----------------
  {
    const int f = wid & 3, half = wid >> 2;
    short8 wA[2][4];
#pragma unroll
    for (int etl = 0; etl < 2; ++etl)
#pragma unroll
      for (int kt = 0; kt < 4; ++kt)
        wA[etl][kt] = *(const short8*)(wsW + (f * 64 + (half * 2 + etl) * 16 + n16) * 128
                                       + kt * 32 + kb);
    f32x4 acc[2];
    acc[0] = (f32x4){0.f,0.f,0.f,0.f}; acc[1] = (f32x4){0.f,0.f,0.f,0.f};
    for (int kt = 0; kt < 4; ++kt) {
      short8 x = *(const short8*)(featB + n16 * 136 + kt * 32 + kb);
      acc[0] = MFMA16(wA[0][kt], x, acc[0]);
      acc[1] = MFMA16(wA[1][kt], x, acc[1]);
    }
#pragma unroll
    for (int etl = 0; etl < 2; ++etl) {
      f32x4 b1q = *(const f32x4*)(cfb1 + f * 64 + (half * 2 + etl) * 16 + q * 4);
      float h0 = lrelu(acc[etl][0] + b1q[0]), h1 = lrelu(acc[etl][1] + b1q[1]);
      float h2 = lrelu(acc[etl][2] + b1q[2]), h3 = lrelu(acc[etl][3] + b1q[3]);
      uint2 pk; pk.x = pk2(h0, h1); pk.y = pk2(h2, h3);
      *(uint2*)(hidS + (f * 16 + n16) * 136 + (half * 2 + etl) * 16 + q * 4) = pk;
    }
    __syncthreads();
    short8 wB[4][2];
#pragma unroll
    for (int ctl = 0; ctl < 4; ++ctl)
#pragma unroll
      for (int kt = 0; kt < 2; ++kt)
        wB[ctl][kt] = *(const short8*)(wsW + 32768 + (f * 128 + half * 64 + ctl * 16 + n16) * 64
                                       + kt * 32 + kb);
    f32x4 acc2[4];
#pragma unroll
    for (int ctl = 0; ctl < 4; ++ctl) acc2[ctl] = (f32x4){0.f,0.f,0.f,0.f};
    for (int kt = 0; kt < 2; ++kt) {
      short8 h = *(const short8*)(hidS + (f * 16 + n16) * 136 + kt * 32 + kb);
#pragma unroll
      for (int ctl = 0; ctl < 4; ++ctl) acc2[ctl] = MFMA16(h, wB[ctl][kt], acc2[ctl]);
    }
#pragma unroll
    for (int ctl = 0; ctl < 4; ++ctl) {
      int c = half * 64 + ctl * 16 + n16;
      float b2 = cfb2[f * 128 + c];
#pragma unroll
      for (int r = 0; r < 4; ++r)
        facL[(q * 4 + r) * 528 + f * 132 + c] = lrelu(acc2[ctl][r] + b2);
    }
    __syncthreads();
  }

  // ---------------- Phase B: inter_factors (fp32 facL state) ----------------
  {
    short8 w1f[4], w2f[4];
#pragma unroll
    for (int kt = 0; kt < 4; ++kt) {
      w1f[kt] = *(const short8*)(wsW + 65536 + col * 128 + kt * 32 + kb);
      w2f[kt] = *(const short8*)(wsW + 81920 + col * 128 + kt * 32 + kb);
    }
    const f32x4 b1q = *(const f32x4*)(f2fb1 + wid * 16 + q * 4);
    const float b2v = f2fb2[col];
    const int rS = tid >> 3, kcS = tid & 7;   // staging: row, 16-value k-chunk
    const int fS = rS & 3, ciS = rS >> 2;
    const int k0 = kcS * 16;

    for (int u = 0; u < nvs; ++u) {
      const int s = vslL[u];
      const int iv = oiL[s];
      const int nc = ncAll[s];
      const int mtn = (nc + 3) >> 2;  // tiles actually consumed below
      // stage prod[r=ci*4+f][k] = bf16(fac[iv][f][k] * fac[cand][f][k])
      if (ciS < nc) {
        const int cit = clAll[s * 16 + ciS];
        const float* tp = facL + iv * 528 + fS * 132;
        const float* cp = facL + cit * 528 + fS * 132;
#pragma unroll
        for (int i2 = 0; i2 < 2; ++i2) {
          const int k = k0 + i2 * 8;
          float4 a0 = *(const float4*)(tp + k), a1 = *(const float4*)(tp + k + 4);
          float4 c0 = *(const float4*)(cp + k), c1 = *(const float4*)(cp + k + 4);
          uint4 u4;
          u4.x = pk2(a0.x * c0.x, a0.y * c0.y); u4.y = pk2(a0.z * c0.z, a0.w * c0.w);
          u4.z = pk2(a1.x * c1.x, a1.y * c1.y); u4.w = pk2(a1.z * c1.z, a1.w * c1.w);
          *(uint4*)(prodS + rS * 136 + k) = u4;
        }
      } else if (ciS < mtn * 4) {  // zero only rows inside consumed tiles
        uint4 z; z.x = z.y = z.z = z.w = 0;
        *(uint4*)(prodS + rS * 136 + k0) = z;
        *(uint4*)(prodS + rS * 136 + k0 + 8) = z;
      }
      __syncthreads();  // [b1] products ready
      // L1 swapped: runtime mt-loop, fresh acc per iter (no conditional defs)
      for (int mt = 0; mt < mtn; ++mt) {
        f32x4 acc = (f32x4){0.f,0.f,0.f,0.f};
#pragma unroll
        for (int kt = 0; kt < 4; ++kt) {
          short8 x = *(const short8*)(prodS + (mt * 16 + n16) * 136 + kt * 32 + kb);
          acc = MFMA16(w1f[kt], x, acc);
        }
        float h0 = lrelu(acc[0] + b1q[0]), h1 = lrelu(acc[1] + b1q[1]);
        float h2 = lrelu(acc[2] + b1q[2]), h3 = lrelu(acc[3] + b1q[3]);
        uint2 pk; pk.x = pk2(h0, h1); pk.y = pk2(h2, h3);
        *(uint2*)(hidS + (mt * 16 + n16) * 136 + wid * 16 + q * 4) = pk;
      }
      __syncthreads();  // [b2] hid ready
      // L2 normal: runtime mt-loop; accumulate masked row-sums into part[]
      float part[4] = {0.f, 0.f, 0.f, 0.f};
      for (int mt = 0; mt < mtn; ++mt) {
        f32x4 acc2 = (f32x4){0.f,0.f,0.f,0.f};
#pragma unroll
        for (int kt = 0; kt < 4; ++kt) {
          short8 h = *(const short8*)(hidS + (mt * 16 + n16) * 136 + kt * 32 + kb);
          acc2 = MFMA16(h, w2f[kt], acc2);
        }
        bool act = (mt * 4 + q) < nc;
        if (act) {
#pragma unroll
          for (int r = 0; r < 4; ++r) part[r] += lrelu(acc2[r] + b2v);
        }
      }
#pragma unroll
      for (int r = 0; r < 4; ++r) {
        float v = part[r];
        v += __shfl_xor(v, 16);
        v += __shfl_xor(v, 32);
        part[r] = v;
      }
      if (q == 0) {  // wave owns cols exclusively -> plain fp32 +=
#pragma unroll
        for (int r = 0; r < 4; ++r)
          facL[iv * 528 + r * 132 + col] += part[r];
      }
      __syncthreads();  // [b3] facL updated for next step's stage
    }
  }

  // ---------------- Phase C: infer_items ----------------
  {
    short8 w1f[4], w2f[4];
#pragma unroll
    for (int kt = 0; kt < 4; ++kt) {
      w1f[kt] = *(const short8*)(wsW + 98304 + col * 128 + kt * 32 + kb);
      w2f[kt] = *(const short8*)(wsW + 114688 + col * 128 + kt * 32 + kb);
    }
    const f32x4 b1q = *(const f32x4*)(f2ib1 + wid * 16 + q * 4);
    const float b2v = f2ib2[col];
    // stage prod[r=item*4+f][k] = bf16(fac[item][f][k])
    {
      const int r = tid >> 3, kc = tid & 7, k0 = kc * 16;
      const int f = r & 3, item = r >> 2;
      const float* sp = facL + item * 528 + f * 132;
#pragma unroll
      for (int i2 = 0; i2 < 2; ++i2) {
        const int k = k0 + i2 * 8;
        float4 a0 = *(const float4*)(sp + k), a1 = *(const float4*)(sp + k + 4);
        uint4 u;
        u.x = pk2(a0.x, a0.y); u.y = pk2(a0.z, a0.w);
        u.z = pk2(a1.x, a1.y); u.w = pk2(a1.z, a1.w);
        *(uint4*)(prodS + r * 136 + k) = u;
      }
    }
    __syncthreads();
    f32x4 acc[4];
#pragma unroll
    for (int mt = 0; mt < 4; ++mt) acc[mt] = (f32x4){0.f,0.f,0.f,0.f};
    for (int kt = 0; kt < 4; ++kt)
#pragma unroll
      for (int mt = 0; mt < 4; ++mt) {
        short8 x = *(const short8*)(prodS + (mt * 16 + n16) * 136 + kt * 32 + kb);
        acc[mt] = MFMA16(w1f[kt], x, acc[mt]);
      }
#pragma unroll
    for (int mt = 0; mt < 4; ++mt) {
      float h0 = lrelu(acc[mt][0] + b1q[0]), h1 = lrelu(acc[mt][1] + b1q[1]);
      float h2 = lrelu(acc[mt][2] + b1q[2]), h3 = lrelu(acc[mt][3] + b1q[3]);
      uint2 pk; pk.x = pk2(h0, h1); pk.y = pk2(h2, h3);
      *(uint2*)(hidS + (mt * 16 + n16) * 136 + wid * 16 + q * 4) = pk;
    }
    __syncthreads();
    f32x4 acc2[4];
#pragma unroll
    for (int mt = 0; mt < 4; ++mt) acc2[mt] = (f32x4){0.f,0.f,0.f,0.f};
    for (int kt = 0; kt < 4; ++kt)
#pragma unroll
      for (int mt = 0; mt < 4; ++mt) {
        short8 h = *(const short8*)(hidS + (mt * 16 + n16) * 136 + kt * 32 + kb);
        acc2[mt] = MFMA16(h, w2f[kt], acc2[mt]);
      }
#pragma unroll
    for (int mt = 0; mt < 4; ++mt) {
      int item = mt * 4 + q;  // rows = item*4+f, f=reg
      float g = 0.f;
#pragma unroll
      for (int r = 0; r < 4; ++r) g += lrelu(acc2[mt][r] + b2v);
      int a = item * 136 + col;  // unique (item,col) per lane
      featB[a] = f2bf(bflo((unsigned)featB[a]) + (float)refcntL[item] * g);
    }
    __syncthreads();
  }

  // ---------------- Phase D: inter_items (featB IS the A operand) ----------------
  {
    short8 w1f[4], w2f[4];
#pragma unroll
    for (int kt = 0; kt < 4; ++kt) {
      w1f[kt] = *(const short8*)(wsW + 131072 + col * 128 + kt * 32 + kb);
      w2f[kt] = *(const short8*)(wsW + 147456 + col * 128 + kt * 32 + kb);
    }
    const f32x4 b1q = *(const f32x4*)(i2ib1 + wid * 16 + q * 4);
    const float b2v = i2ib2[col];

    for (int u = 0; u < nvs; ++u) {
      const int iv = oiL[vslL[u]];
      f32x4 acc = (f32x4){0.f,0.f,0.f,0.f};
      for (int kt = 0; kt < 4; ++kt) {
        short8 x = *(const short8*)(featB + n16 * 136 + kt * 32 + kb);
        acc = MFMA16(w1f[kt], x, acc);
      }
      {
        float h0 = lrelu(acc[0] + b1q[0]), h1 = lrelu(acc[1] + b1q[1]);
        float h2 = lrelu(acc[2] + b1q[2]), h3 = lrelu(acc[3] + b1q[3]);
        uint2 pk; pk.x = pk2(h0, h1); pk.y = pk2(h2, h3);
        *(uint2*)(hidS + n16 * 136 + wid * 16 + q * 4) = pk;
      }
      __syncthreads();
      f32x4 acc2 = (f32x4){0.f,0.f,0.f,0.f};
      for (int kt = 0; kt < 4; ++kt) {
        short8 h = *(const short8*)(hidS + n16 * 136 + kt * 32 + kb);
        acc2 = MFMA16(h, w2f[kt], acc2);
      }
      // msgs summed per item with weight = (item==iv) ? 0 : refcnt[item]
      float part = 0.f;
#pragma unroll
      for (int r = 0; r < 4; ++r) {
        int item = q * 4 + r;
        float w = (item == iv) ? 0.0f : (float)refcntL[item];
        part += w * lrelu(acc2[r] + b2v);
      }
      part += __shfl_xor(part, 16);
      part += __shfl_xor(part, 32);
      if (q == 0) {
        int a = iv * 136 + col;
        featB[a] = f2bf(bflo((unsigned)featB[a]) + part);
      }
      __syncthreads();
    }
  }

  // ---------------- Phase E: infer_outfit + score ----------------
  if (tid < 128) {
    float sum = 0.0f;
    for (int u = 0; u < nvs; ++u)
      sum += bflo((unsigned)featB[oiL[vslL[u]] * 136 + tid]);
    float v = sum * o2sW[tid];
#pragma unroll
    for (int off = 1; off < 64; off <<= 1) v += __shfl_xor(v, off);
    if (lane == 0) redE[wid] = v;
  }
  __syncthreads();
  if (tid == 0) {
    float t = redE[0] + redE[1] + o2sb[0];
    out[o] = 1.0f / (1.0f + expf(-t));
  }

  // ---------------- Phase F: com_loss from fp32 facL ----------------
  {
    const int n = tid >> 5, f = (tid >> 3) & 3, g = (tid >> 1) & 3, h = tid & 1;
    const float* pa = facL + n * 528 + f * 132 + h * 64;
    const float* pb = facL + n * 528 + g * 132 + h * 64;
    float dot = 0.0f;
    for (int i = 0; i < 16; ++i) {
      float4 a = *(const float4*)(pa + i * 4);
      float4 b = *(const float4*)(pb + i * 4);
      dot += a.x * b.x + a.y * b.y + a.z * b.z + a.w * b.w;
    }
    dot += __shfl_xor(dot, 1);  // combine k-halves
    float v = dot - ((f == g) ? 1.0f : 0.0f);
    float sq = (h == 0 && oiL[n] != -1) ? v * v : 0.0f;
#pragma unroll
    for (int off = 1; off < 64; off <<= 1) sq += __shfl_xor(sq, off);
    __syncthreads();  // E's redE read complete before overwrite
    if (lane == 0) redE[wid] = sq;
    __syncthreads();
    if (tid == 0) {
      float tot = 0.f;
#pragma unroll
      for (int w = 0; w < 8; ++w) tot += redE[w];
      atomicAdd(out + 2048, tot * (1.0f / 2048.0f));
    }
  }
}

extern "C" void kernel_launch(void* const* d_in, const int* in_sizes, int n_in,
                              void* d_out, int out_size, void* d_ws, size_t ws_size,
                              hipStream_t stream) {
  float* out = (float*)d_out;
  ushort* ws = (ushort*)d_ws;  // needs 320KB
  hipLaunchKernelGGL(prep_weights, dim3(640), dim3(256), 0, stream,
                     (const float*)d_in[4], (const float*)d_in[6],
                     (const float*)d_in[8], (const float*)d_in[10],
                     (const float*)d_in[12], (const float*)d_in[14],
                     (const float*)d_in[16], (const float*)d_in[18],
                     ws, out);
  hipLaunchKernelGGL(mfgn_kernel, dim3(2048), dim3(512), 0, stream,
                     (const int*)d_in[0],
                     (const float*)d_in[1],
                     (const int*)d_in[2],
                     // d_in[3] items_factors unused; weights via ws
                     (const float*)d_in[5], (const float*)d_in[7],
                     (const float*)d_in[9], (const float*)d_in[11],
                     (const float*)d_in[13], (const float*)d_in[15],
                     (const float*)d_in[17], (const float*)d_in[19],
                     (const float*)d_in[20], (const float*)d_in[21],
                     (const ushort*)ws,
                     out);
}

// Round 13
// 336.891 us; speedup vs baseline: 1.0290x; 1.0104x over previous
//
#include <hip/hip_runtime.h>
#include <hip/hip_bf16.h>
#include <math.h>

// MFGN forward, MI355X. One block (512 thr, 8 waves) per outfit.
// fp32 facL state in LDS; bf16 featB state in MFMA A-layout; separate
// prod/hid buffers (B: 3 barriers/step); weights pre-transposed to bf16
// [N][K] in d_ws (one dwordx4 per fragment).
// R13 VALU diet: lrelu=fmax(x,.01x) (2 ops), bias pre-loaded into MFMA
// accumulator init (no epilogue adds), Phase B mt-loops re-unrolled to
// compile-time 4 (imm ds_read offsets; runtime-mtn bought nothing at
// nc~14.5 and cost per-mt address math). No conditional acc defs anywhere
// (R8/R9 spill lesson). 2 blocks/CU is an LDS floor (fp32 facL 32KB min).

typedef __attribute__((ext_vector_type(8))) short short8;
typedef __attribute__((ext_vector_type(4))) float f32x4;

#define MFMA16(a, b, c) __builtin_amdgcn_mfma_f32_16x16x32_bf16(a, b, c, 0, 0, 0)

__device__ __forceinline__ float lrelu(float x) { return fmaxf(x, 0.01f * x); }

__device__ __forceinline__ ushort f2bf(float f) {
  unsigned u = __builtin_bit_cast(unsigned, f);
  u += 0x7fffu + ((u >> 16) & 1u);  // RNE
  return (ushort)(u >> 16);
}
__device__ __forceinline__ float bflo(unsigned u) {
  return __builtin_bit_cast(float, u << 16);
}
__device__ __forceinline__ unsigned pk2(float a, float b) {
  float2 t; t.x = a; t.y = b;
  __hip_bfloat162 h = __float22bfloat162_rn(t);
  unsigned u;
  __builtin_memcpy(&u, &h, 4);
  return u;
}

// d_ws layout (ushort): cfW1T@0 [4][64n][128k] | cfW2T@32768 [4][128n][64k]
// | f2fW1T@65536 | f2fW2T@81920 | f2iW1T@98304 | f2iW2T@114688
// | i2iW1T@131072 | i2iW2T@147456   ([128n][128k] each; 320KB total)

__global__ __launch_bounds__(256) void prep_weights(
    const float* __restrict__ cfW1, const float* __restrict__ cfW2,
    const float* __restrict__ f2fW1, const float* __restrict__ f2fW2,
    const float* __restrict__ f2iW1, const float* __restrict__ f2iW2,
    const float* __restrict__ i2iW1, const float* __restrict__ i2iW2,
    ushort* __restrict__ ws, float* __restrict__ out) {
  const int idx = (int)(blockIdx.x * 256 + threadIdx.x);
  if (idx == 0) out[2048] = 0.0f;  // com accumulator zero
  float v;
  if (idx < 32768) {          // cfW1 [f][k<128][n<64] -> [f][n][k]
    int f = idx >> 13, r = idx & 8191, n = r >> 7, k = r & 127;
    v = cfW1[f * 8192 + k * 64 + n];
  } else if (idx < 65536) {   // cfW2 [f][k<64][n<128] -> [f][n][k]
    int t = idx - 32768;
    int f = t >> 13, r = t & 8191, n = r >> 6, k = r & 63;
    v = cfW2[f * 8192 + k * 128 + n];
  } else {                    // 6 x [k<128][n<128] -> [n][k]
    int t = idx - 65536;
    int seg = t >> 14, r = t & 16383, n = r >> 7, k = r & 127;
    const float* W = (seg == 0) ? f2fW1 : (seg == 1) ? f2fW2 :
                     (seg == 2) ? f2iW1 : (seg == 3) ? f2iW2 :
                     (seg == 4) ? i2iW1 : i2iW2;
    v = W[k * 128 + n];
  }
  ws[idx] = f2bf(v);
}

__global__ __launch_bounds__(512, 4) void mfgn_kernel(
    const int* __restrict__ outfit_items,
    const float* __restrict__ items_feature,
    const int* __restrict__ items_neighbor,
    const float* __restrict__ cfb1, const float* __restrict__ cfb2,
    const float* __restrict__ f2fb1, const float* __restrict__ f2fb2,
    const float* __restrict__ f2ib1, const float* __restrict__ f2ib2,
    const float* __restrict__ i2ib1, const float* __restrict__ i2ib2,
    const float* __restrict__ o2sW, const float* __restrict__ o2sb,
    const ushort* __restrict__ wsW,
    float* __restrict__ out)
{
  __shared__ float facL[16 * 528];                                 // 33792 B fp32 state
  __shared__ ushort prodS[64 * 136] __attribute__((aligned(16)));  // 17408 B bf16 A-staging
  __shared__ ushort hidS[64 * 136] __attribute__((aligned(16)));   // 17408 B bf16 hidden
  __shared__ ushort featB[16 * 136] __attribute__((aligned(16)));  //  4352 B bf16 feat state
  __shared__ float redE[8];
  __shared__ int oiL[16];
  __shared__ int clAll[256];
  __shared__ int ncAll[16];
  __shared__ int vslL[16];
  __shared__ int refcntL[16];
  __shared__ int nvsL;

  const int o = blockIdx.x;
  const int tid = (int)threadIdx.x;
  const int lane = tid & 63;
  const int wid = tid >> 6;        // wave owns output cols wid*16..+15
  const int n16 = lane & 15;
  const int q = lane >> 4;
  const int kb = q * 8;
  const int col = wid * 16 + n16;

  // ---------------- load inputs ----------------
  if (tid < 16) oiL[tid] = outfit_items[o * 16 + tid];
  {
    const int n = tid >> 5, d0 = (tid & 31) * 4;
    float4 v = *(const float4*)(items_feature + o * 2048 + tid * 4);
    uint2 pk; pk.x = pk2(v.x, v.y); pk.y = pk2(v.z, v.w);
    *(uint2*)(featB + n * 136 + d0) = pk;
  }
  if (tid == 0) {
    int cnt = 0;
    for (int s = 0; s < 16; ++s) refcntL[s] = 0;
    for (int s = 0; s < 16; ++s) {
      int v = oiL[s];
      if (v != -1) { vslL[cnt++] = s; refcntL[v]++; }
    }
    nvsL = cnt;
  }
  for (int s = wid; s < 16; s += 8) {
    const int iv = outfit_items[o * 16 + s];
    if (iv == -1) { if (lane == 0) ncAll[s] = 0; continue; }
    int cand = -1;
    if (lane < 24) cand = (lane < 16) ? outfit_items[o * 16 + lane]
                                      : items_neighbor[o * 128 + iv * 8 + (lane - 16)];
    bool ok = (lane < 24) && (cand != -1) && (cand != iv);
    unsigned long long bm = __ballot(ok);
    if (ok) clAll[s * 16 + __popcll(bm & ((1ull << lane) - 1ull))] = cand;
    if (lane == 0) ncAll[s] = (int)__popcll(bm);
  }
  __syncthreads();
  const int nvs = nvsL;

  // ---------------- Phase A: creat_factors ----------------
  {
    const int f = wid & 3, half = wid >> 2;
    short8 wA[2][4];
#pragma unroll
    for (int etl = 0; etl < 2; ++etl)
#pragma unroll
      for (int kt = 0; kt < 4; ++kt)
        wA[etl][kt] = *(const short8*)(wsW + (f * 64 + (half * 2 + etl) * 16 + n16) * 128
                                       + kt * 32 + kb);
    f32x4 acc[2];
#pragma unroll
    for (int etl = 0; etl < 2; ++etl)
      acc[etl] = *(const f32x4*)(cfb1 + f * 64 + (half * 2 + etl) * 16 + q * 4);  // bias init
    for (int kt = 0; kt < 4; ++kt) {
      short8 x = *(const short8*)(featB + n16 * 136 + kt * 32 + kb);
      acc[0] = MFMA16(wA[0][kt], x, acc[0]);
      acc[1] = MFMA16(wA[1][kt], x, acc[1]);
    }
#pragma unroll
    for (int etl = 0; etl < 2; ++etl) {
      float h0 = lrelu(acc[etl][0]), h1 = lrelu(acc[etl][1]);
      float h2 = lrelu(acc[etl][2]), h3 = lrelu(acc[etl][3]);
      uint2 pk; pk.x = pk2(h0, h1); pk.y = pk2(h2, h3);
      *(uint2*)(hidS + (f * 16 + n16) * 136 + (half * 2 + etl) * 16 + q * 4) = pk;
    }
    __syncthreads();
    short8 wB[4][2];
#pragma unroll
    for (int ctl = 0; ctl < 4; ++ctl)
#pragma unroll
      for (int kt = 0; kt < 2; ++kt)
        wB[ctl][kt] = *(const short8*)(wsW + 32768 + (f * 128 + half * 64 + ctl * 16 + n16) * 64
                                       + kt * 32 + kb);
    f32x4 acc2[4];
#pragma unroll
    for (int ctl = 0; ctl < 4; ++ctl) {
      float b2 = cfb2[f * 128 + half * 64 + ctl * 16 + n16];
      acc2[ctl] = (f32x4){b2, b2, b2, b2};  // bias init
    }
    for (int kt = 0; kt < 2; ++kt) {
      short8 h = *(const short8*)(hidS + (f * 16 + n16) * 136 + kt * 32 + kb);
#pragma unroll
      for (int ctl = 0; ctl < 4; ++ctl) acc2[ctl] = MFMA16(h, wB[ctl][kt], acc2[ctl]);
    }
#pragma unroll
    for (int ctl = 0; ctl < 4; ++ctl) {
      int c = half * 64 + ctl * 16 + n16;
#pragma unroll
      for (int r = 0; r < 4; ++r)
        facL[(q * 4 + r) * 528 + f * 132 + c] = lrelu(acc2[ctl][r]);
    }
    __syncthreads();
  }

  // ---------------- Phase B: inter_factors (fp32 facL state) ----------------
  {
    short8 w1f[4], w2f[4];
#pragma unroll
    for (int kt = 0; kt < 4; ++kt) {
      w1f[kt] = *(const short8*)(wsW + 65536 + col * 128 + kt * 32 + kb);
      w2f[kt] = *(const short8*)(wsW + 81920 + col * 128 + kt * 32 + kb);
    }
    const f32x4 b1q = *(const f32x4*)(f2fb1 + wid * 16 + q * 4);
    const float b2v = f2fb2[col];
    const int rS = tid >> 3, kcS = tid & 7;   // staging: row, 16-value k-chunk
    const int fS = rS & 3, ciS = rS >> 2;
    const int k0 = kcS * 16;

    for (int u = 0; u < nvs; ++u) {
      const int s = vslL[u];
      const int iv = oiL[s];
      const int nc = ncAll[s];
      // stage prod[r=ci*4+f][k] = bf16(fac[iv][f][k] * fac[cand][f][k])
      if (ciS < nc) {
        const int cit = clAll[s * 16 + ciS];
        const float* tp = facL + iv * 528 + fS * 132;
        const float* cp = facL + cit * 528 + fS * 132;
#pragma unroll
        for (int i2 = 0; i2 < 2; ++i2) {
          const int k = k0 + i2 * 8;
          float4 a0 = *(const float4*)(tp + k), a1 = *(const float4*)(tp + k + 4);
          float4 c0 = *(const float4*)(cp + k), c1 = *(const float4*)(cp + k + 4);
          uint4 u4;
          u4.x = pk2(a0.x * c0.x, a0.y * c0.y); u4.y = pk2(a0.z * c0.z, a0.w * c0.w);
          u4.z = pk2(a1.x * c1.x, a1.y * c1.y); u4.w = pk2(a1.z * c1.z, a1.w * c1.w);
          *(uint4*)(prodS + rS * 136 + k) = u4;
        }
      } else {
        uint4 z; z.x = z.y = z.z = z.w = 0;
        *(uint4*)(prodS + rS * 136 + k0) = z;
        *(uint4*)(prodS + rS * 136 + k0 + 8) = z;
      }
      __syncthreads();  // [b1] products ready
      // L1 swapped: unrolled 4 tiles, bias-initialized acc
      f32x4 acc[4];
#pragma unroll
      for (int mt = 0; mt < 4; ++mt) acc[mt] = b1q;
      for (int kt = 0; kt < 4; ++kt)
#pragma unroll
        for (int mt = 0; mt < 4; ++mt) {
          short8 x = *(const short8*)(prodS + (mt * 16 + n16) * 136 + kt * 32 + kb);
          acc[mt] = MFMA16(w1f[kt], x, acc[mt]);
        }
#pragma unroll
      for (int mt = 0; mt < 4; ++mt) {
        float h0 = lrelu(acc[mt][0]), h1 = lrelu(acc[mt][1]);
        float h2 = lrelu(acc[mt][2]), h3 = lrelu(acc[mt][3]);
        uint2 pk; pk.x = pk2(h0, h1); pk.y = pk2(h2, h3);
        *(uint2*)(hidS + (mt * 16 + n16) * 136 + wid * 16 + q * 4) = pk;
      }
      __syncthreads();  // [b2] hid ready
      // L2 normal: unrolled 4 tiles, bias-initialized acc
      f32x4 acc2[4];
#pragma unroll
      for (int mt = 0; mt < 4; ++mt) acc2[mt] = (f32x4){b2v, b2v, b2v, b2v};
      for (int kt = 0; kt < 4; ++kt)
#pragma unroll
        for (int mt = 0; mt < 4; ++mt) {
          short8 h = *(const short8*)(hidS + (mt * 16 + n16) * 136 + kt * 32 + kb);
          acc2[mt] = MFMA16(h, w2f[kt], acc2[mt]);
        }
      // epilogue: rows ci*4+f (f=reg); mask ci=mt*4+q<nc; sum over ci
      float part[4] = {0.f, 0.f, 0.f, 0.f};
#pragma unroll
      for (int mt = 0; mt < 4; ++mt) {
        bool act = (mt * 4 + q) < nc;
        if (act) {
#pragma unroll
          for (int r = 0; r < 4; ++r) part[r] += lrelu(acc2[mt][r]);
        }
      }
#pragma unroll
      for (int r = 0; r < 4; ++r) {
        float v = part[r];
        v += __shfl_xor(v, 16);
        v += __shfl_xor(v, 32);
        part[r] = v;
      }
      if (q == 0) {  // wave owns cols exclusively -> plain fp32 +=
#pragma unroll
        for (int r = 0; r < 4; ++r)
          facL[iv * 528 + r * 132 + col] += part[r];
      }
      __syncthreads();  // [b3] facL updated for next step's stage
    }
  }

  // ---------------- Phase C: infer_items ----------------
  {
    short8 w1f[4], w2f[4];
#pragma unroll
    for (int kt = 0; kt < 4; ++kt) {
      w1f[kt] = *(const short8*)(wsW + 98304 + col * 128 + kt * 32 + kb);
      w2f[kt] = *(const short8*)(wsW + 114688 + col * 128 + kt * 32 + kb);
    }
    const f32x4 b1q = *(const f32x4*)(f2ib1 + wid * 16 + q * 4);
    const float b2v = f2ib2[col];
    // stage prod[r=item*4+f][k] = bf16(fac[item][f][k])
    {
      const int r = tid >> 3, kc = tid & 7, k0 = kc * 16;
      const int f = r & 3, item = r >> 2;
      const float* sp = facL + item * 528 + f * 132;
#pragma unroll
      for (int i2 = 0; i2 < 2; ++i2) {
        const int k = k0 + i2 * 8;
        float4 a0 = *(const float4*)(sp + k), a1 = *(const float4*)(sp + k + 4);
        uint4 u;
        u.x = pk2(a0.x, a0.y); u.y = pk2(a0.z, a0.w);
        u.z = pk2(a1.x, a1.y); u.w = pk2(a1.z, a1.w);
        *(uint4*)(prodS + r * 136 + k) = u;
      }
    }
    __syncthreads();
    f32x4 acc[4];
#pragma unroll
    for (int mt = 0; mt < 4; ++mt) acc[mt] = b1q;
    for (int kt = 0; kt < 4; ++kt)
#pragma unroll
      for (int mt = 0; mt < 4; ++mt) {
        short8 x = *(const short8*)(prodS + (mt * 16 + n16) * 136 + kt * 32 + kb);
        acc[mt] = MFMA16(w1f[kt], x, acc[mt]);
      }
#pragma unroll
    for (int mt = 0; mt < 4; ++mt) {
      float h0 = lrelu(acc[mt][0]), h1 = lrelu(acc[mt][1]);
      float h2 = lrelu(acc[mt][2]), h3 = lrelu(acc[mt][3]);
      uint2 pk; pk.x = pk2(h0, h1); pk.y = pk2(h2, h3);
      *(uint2*)(hidS + (mt * 16 + n16) * 136 + wid * 16 + q * 4) = pk;
    }
    __syncthreads();
    f32x4 acc2[4];
#pragma unroll
    for (int mt = 0; mt < 4; ++mt) acc2[mt] = (f32x4){b2v, b2v, b2v, b2v};
    for (int kt = 0; kt < 4; ++kt)
#pragma unroll
      for (int mt = 0; mt < 4; ++mt) {
        short8 h = *(const short8*)(hidS + (mt * 16 + n16) * 136 + kt * 32 + kb);
        acc2[mt] = MFMA16(h, w2f[kt], acc2[mt]);
      }
#pragma unroll
    for (int mt = 0; mt < 4; ++mt) {
      int item = mt * 4 + q;  // rows = item*4+f, f=reg
      float g = 0.f;
#pragma unroll
      for (int r = 0; r < 4; ++r) g += lrelu(acc2[mt][r]);
      int a = item * 136 + col;  // unique (item,col) per lane
      featB[a] = f2bf(bflo((unsigned)featB[a]) + (float)refcntL[item] * g);
    }
    __syncthreads();
  }

  // ---------------- Phase D: inter_items (featB IS the A operand) ----------------
  {
    short8 w1f[4], w2f[4];
#pragma unroll
    for (int kt = 0; kt < 4; ++kt) {
      w1f[kt] = *(const short8*)(wsW + 131072 + col * 128 + kt * 32 + kb);
      w2f[kt] = *(const short8*)(wsW + 147456 + col * 128 + kt * 32 + kb);
    }
    const f32x4 b1q = *(const f32x4*)(i2ib1 + wid * 16 + q * 4);
    const float b2v = i2ib2[col];

    for (int u = 0; u < nvs; ++u) {
      const int iv = oiL[vslL[u]];
      f32x4 acc = b1q;
      for (int kt = 0; kt < 4; ++kt) {
        short8 x = *(const short8*)(featB + n16 * 136 + kt * 32 + kb);
        acc = MFMA16(w1f[kt], x, acc);
      }
      {
        float h0 = lrelu(acc[0]), h1 = lrelu(acc[1]);
        float h2 = lrelu(acc[2]), h3 = lrelu(acc[3]);
        uint2 pk; pk.x = pk2(h0, h1); pk.y = pk2(h2, h3);
        *(uint2*)(hidS + n16 * 136 + wid * 16 + q * 4) = pk;
      }
      __syncthreads();
      f32x4 acc2 = (f32x4){b2v, b2v, b2v, b2v};
      for (int kt = 0; kt < 4; ++kt) {
        short8 h = *(const short8*)(hidS + n16 * 136 + kt * 32 + kb);
        acc2 = MFMA16(h, w2f[kt], acc2);
      }
      // msgs summed per item with weight = (item==iv) ? 0 : refcnt[item]
      float part = 0.f;
#pragma unroll
      for (int r = 0; r < 4; ++r) {
        int item = q * 4 + r;
        float w = (item == iv) ? 0.0f : (float)refcntL[item];
        part += w * lrelu(acc2[r]);
      }
      part += __shfl_xor(part, 16);
      part += __shfl_xor(part, 32);
      if (q == 0) {
        int a = iv * 136 + col;
        featB[a] = f2bf(bflo((unsigned)featB[a]) + part);
      }
      __syncthreads();
    }
  }

  // ---------------- Phase E: infer_outfit + score ----------------
  if (tid < 128) {
    float sum = 0.0f;
    for (int u = 0; u < nvs; ++u)
      sum += bflo((unsigned)featB[oiL[vslL[u]] * 136 + tid]);
    float v = sum * o2sW[tid];
#pragma unroll
    for (int off = 1; off < 64; off <<= 1) v += __shfl_xor(v, off);
    if (lane == 0) redE[wid] = v;
  }
  __syncthreads();
  if (tid == 0) {
    float t = redE[0] + redE[1] + o2sb[0];
    out[o] = 1.0f / (1.0f + expf(-t));
  }

  // ---------------- Phase F: com_loss from fp32 facL ----------------
  {
    const int n = tid >> 5, f = (tid >> 3) & 3, g = (tid >> 1) & 3, h = tid & 1;
    const float* pa = facL + n * 528 + f * 132 + h * 64;
    const float* pb = facL + n * 528 + g * 132 + h * 64;
    float dot = 0.0f;
    for (int i = 0; i < 16; ++i) {
      float4 a = *(const float4*)(pa + i * 4);
      float4 b = *(const float4*)(pb + i * 4);
      dot += a.x * b.x + a.y * b.y + a.z * b.z + a.w * b.w;
    }
    dot += __shfl_xor(dot, 1);  // combine k-halves
    float v = dot - ((f == g) ? 1.0f : 0.0f);
    float sq = (h == 0 && oiL[n] != -1) ? v * v : 0.0f;
#pragma unroll
    for (int off = 1; off < 64; off <<= 1) sq += __shfl_xor(sq, off);
    __syncthreads();  // E's redE read complete before overwrite
    if (lane == 0) redE[wid] = sq;
    __syncthreads();
    if (tid == 0) {
      float tot = 0.f;
#pragma unroll
      for (int w = 0; w < 8; ++w) tot += redE[w];
      atomicAdd(out + 2048, tot * (1.0f / 2048.0f));
    }
  }
}

extern "C" void kernel_launch(void* const* d_in, const int* in_sizes, int n_in,
                              void* d_out, int out_size, void* d_ws, size_t ws_size,
                              hipStream_t stream) {
  float* out = (float*)d_out;
  ushort* ws = (ushort*)d_ws;  // needs 320KB
  hipLaunchKernelGGL(prep_weights, dim3(640), dim3(256), 0, stream,
                     (const float*)d_in[4], (const float*)d_in[6],
                     (const float*)d_in[8], (const float*)d_in[10],
                     (const float*)d_in[12], (const float*)d_in[14],
                     (const float*)d_in[16], (const float*)d_in[18],
                     ws, out);
  hipLaunchKernelGGL(mfgn_kernel, dim3(2048), dim3(512), 0, stream,
                     (const int*)d_in[0],
                     (const float*)d_in[1],
                     (const int*)d_in[2],
                     // d_in[3] items_factors unused; weights via ws
                     (const float*)d_in[5], (const float*)d_in[7],
                     (const float*)d_in[9], (const float*)d_in[11],
                     (const float*)d_in[13], (const float*)d_in[15],
                     (const float*)d_in[17], (const float*)d_in[19],
                     (const float*)d_in[20], (const float*)d_in[21],
                     (const ushort*)ws,
                     out);
}